// Round 1
// baseline (205.015 us; speedup 1.0000x reference)
//
#include <hip/hip_runtime.h>
#include <hip/hip_bf16.h>

#define NN      50000
#define INDIM   512
#define HIDDEN  256
#define NE      800000
#define BIASF   0.0001f

typedef __attribute__((ext_vector_type(4))) float  f32x4;
typedef __attribute__((ext_vector_type(4))) __bf16 bf16x4;
typedef __attribute__((ext_vector_type(8))) __bf16 bf16x8;

// ---------------------------------------------------------------------------
// prep: blocks 0..31 : Wtb[n][k] = (bf16)W_emb[k][n] via coalesced LDS transpose
//       block  32    : w_sym[j] = 0.5*(We[j]+We[j+256])
// ---------------------------------------------------------------------------
__global__ __launch_bounds__(256) void prep_kernel(const float* __restrict__ W_emb,
                                                   const float* __restrict__ W_edge,
                                                   __bf16* __restrict__ Wtb,
                                                   float* __restrict__ w_sym) {
    const int b   = blockIdx.x;
    const int tid = threadIdx.x;
    if (b < 32) {
        __shared__ float t[64 * 65];
        const int kt = (b >> 2) * 64;
        const int nt = (b & 3) * 64;
        const int rr = tid >> 4;           // 0..15
        const int cc = (tid & 15) * 4;     // 0..60
#pragma unroll
        for (int p = 0; p < 4; ++p) {
            int r = p * 16 + rr;
            f32x4 v = *(const f32x4*)&W_emb[(size_t)(kt + r) * HIDDEN + nt + cc];
            t[(cc + 0) * 65 + r] = v[0];
            t[(cc + 1) * 65 + r] = v[1];
            t[(cc + 2) * 65 + r] = v[2];
            t[(cc + 3) * 65 + r] = v[3];
        }
        __syncthreads();
#pragma unroll
        for (int p = 0; p < 4; ++p) {
            int n = p * 16 + rr;
            bf16x4 o;
            o[0] = (__bf16)t[n * 65 + cc + 0];
            o[1] = (__bf16)t[n * 65 + cc + 1];
            o[2] = (__bf16)t[n * 65 + cc + 2];
            o[3] = (__bf16)t[n * 65 + cc + 3];
            *(bf16x4*)&Wtb[(size_t)(nt + n) * INDIM + kt + cc] = o;
        }
    } else {
        w_sym[tid] = 0.5f * (W_edge[tid] + W_edge[tid + HIDDEN]);
    }
}

// ---------------------------------------------------------------------------
// gemm_g v2: reg-staged A (plain dwordx4 loads = proven 6.3 TB/s path),
// fp32->bf16 convert in regs during staging, bf16 LDS tiles (half the LDS
// traffic, zero inner-loop cvt), XOR-swizzled layout (byte ^= (row&7)<<4:
// fragment ds_read_b128 lands 2-way = free [m136]), and a 2-chunk (K=256)
// double-buffered pipeline with issue-early/write-late [T14]: chunk-1 global
// loads fly across compute(0); their ds_writes land after it with incremental
// vmcnt waits. One barrier per chunk, no vmcnt(0) convoy drain.
//   g[m] = sum_n relu(emb[m]@W[:,n] + b[n]) * w_sym[n]
// ---------------------------------------------------------------------------
__global__ __launch_bounds__(256, 2) void gemm_g_kernel(const float* __restrict__ A,
                                                        const __bf16* __restrict__ Wtb,
                                                        const float* __restrict__ bias,
                                                        const float* __restrict__ w_sym,
                                                        float* __restrict__ g) {
    __shared__ __align__(16) __bf16 As[2][64 * 256];   // 2 x 32 KiB bf16
    __shared__ float red[4][64];                       // +1 KiB -> 2 blocks/CU

    const int tid  = threadIdx.x;
    const int lane = tid & 63;
    const int w    = tid >> 6;                   // wave id = N-quarter
    const int ml   = lane & 15, kq = lane >> 4;
    const int m0   = blockIdx.x * 64;
    const int sml  = (ml & 7) << 4;              // read-side swizzle constant

    f32x4 acc[4][4];
#pragma unroll
    for (int i = 0; i < 4; ++i)
#pragma unroll
        for (int j = 0; j < 4; ++j) acc[i][j] = (f32x4)0.0f;

    const __bf16* bp[4];
#pragma unroll
    for (int nt = 0; nt < 4; ++nt) {
        int col = w * 64 + nt * 16 + ml;
        bp[nt] = Wtb + (size_t)col * INDIM + kq * 8;
    }

    // wave w owns rows w*16..w*16+15; one full f32 row (1 KB) per wave-load.
    auto stage_load = [&](f32x4* st, int c) {
#pragma unroll
        for (int j = 0; j < 16; ++j) {
            int gr = m0 + w * 16 + j;
            if (gr > NN - 1) gr = NN - 1;        // M-tail clamp
            st[j] = *(const f32x4*)(A + (size_t)gr * INDIM + c * 256 + lane * 4);
        }
    };
    // cvt to bf16 in regs, ds_write_b64 one row per instr at swizzled slots
    auto stage_write = [&](const f32x4* st, int b) {
        char* lb = (char*)&As[b][0];
#pragma unroll
        for (int j = 0; j < 16; ++j) {
            int r = w * 16 + j;
            bf16x4 o;
            o[0] = (__bf16)st[j][0]; o[1] = (__bf16)st[j][1];
            o[2] = (__bf16)st[j][2]; o[3] = (__bf16)st[j][3];
            *(bf16x4*)(lb + r * 512 + ((lane * 8) ^ ((r & 7) << 4))) = o;
        }
    };
    // 8 ksteps of K=32; fragments are direct bf16x8 ds_read_b128 (no cvt)
    auto compute = [&](int b, int c) {
        const char* lb = (const char*)&As[b][0];
#pragma unroll
        for (int ks = 0; ks < 8; ++ks) {
            bf16x8 af[4], bfr[4];
            const int voff = (ks * 64 + kq * 16) ^ sml;
#pragma unroll
            for (int mt = 0; mt < 4; ++mt)
                af[mt] = *(const bf16x8*)(lb + (mt * 16 + ml) * 512 + voff);
#pragma unroll
            for (int nt = 0; nt < 4; ++nt)
                bfr[nt] = *(const bf16x8*)(bp[nt] + c * 256 + ks * 32);
#pragma unroll
            for (int mt = 0; mt < 4; ++mt)
#pragma unroll
                for (int nt = 0; nt < 4; ++nt)
                    acc[mt][nt] = __builtin_amdgcn_mfma_f32_16x16x32_bf16(
                        af[mt], bfr[nt], acc[mt][nt], 0, 0, 0);
        }
    };

    f32x4 st[16];                               // 64 VGPR staging block
    stage_load(st, 0);
    stage_write(st, 0);                         // incremental vmcnt waits
    __syncthreads();                            // chunk 0 visible to all waves

    stage_load(st, 1);                          // 16 KB/wave in flight across compute(0)
    __builtin_amdgcn_sched_barrier(0);          // pin prefetch above the MFMA cluster
    compute(0, 0);
    stage_write(st, 1);                         // loads ~arrived under compute(0)
    __syncthreads();
    compute(1, 1);

    // ---- epilogue: relu+dot w_sym, xor-reduce over ml lanes, cross-wave LDS ----
    // C/D layout: col = ml, row = kq*4 + reg  [verified m89/m91]
    float wsv[4], bcv[4];
#pragma unroll
    for (int nt = 0; nt < 4; ++nt) {
        int col = w * 64 + nt * 16 + ml;
        wsv[nt] = w_sym[col];
        bcv[nt] = bias[col];
    }
#pragma unroll
    for (int mt = 0; mt < 4; ++mt) {
#pragma unroll
        for (int r = 0; r < 4; ++r) {
            float s = 0.0f;
#pragma unroll
            for (int nt = 0; nt < 4; ++nt) {
                float x = acc[mt][nt][r] + bcv[nt];
                s = fmaf(fmaxf(x, 0.0f), wsv[nt], s);
            }
            s += __shfl_xor(s, 1);
            s += __shfl_xor(s, 2);
            s += __shfl_xor(s, 4);
            s += __shfl_xor(s, 8);
            if (ml == 0) red[w][mt * 16 + kq * 4 + r] = s;
        }
    }
    __syncthreads();
    if (tid < 64) {
        int row = m0 + tid;
        if (row < NN)
            g[row] = red[0][tid] + red[1][tid] + red[2][tid] + red[3][tid];
    }
}

// ---------------------------------------------------------------------------
// edge kernel: one thread per edge; g gathers are 4B L2 hits in a 200 KB array.
// Fused gumbel-sigmoid: sigmoid(log(eps)-log1p(-eps)+raw) = 1/(1+(1/eps-1)e^-raw)
// (one __expf + two divides; robust at both saturation ends; err << tolerance)
// ---------------------------------------------------------------------------
__global__ __launch_bounds__(256) void edge_kernel(const float* __restrict__ g,
                                                   const int* __restrict__ edges,
                                                   const float* __restrict__ u,
                                                   const float* __restrict__ b_edge,
                                                   float* __restrict__ out) {
    const int e  = blockIdx.x * 256 + threadIdx.x;      // NE = 3125*256 exactly
    const int i0 = edges[e];
    const int i1 = edges[NE + e];
    float raw = g[i0] + g[i1] + b_edge[0];
    float uu  = u[e];
    float eps = fmaf(uu, BIASF - (1.0f - BIASF), 1.0f - BIASF); // -0.9998u+0.9999
    float q   = 1.0f / eps - 1.0f;                      // (1-eps)/eps in (1e-4, 1e4)
    float t   = __expf(-raw);
    out[e] = 1.0f / fmaf(q, t, 1.0f);
}

// ---------------------------------------------------------------------------
extern "C" void kernel_launch(void* const* d_in, const int* in_sizes, int n_in,
                              void* d_out, int out_size, void* d_ws, size_t ws_size,
                              hipStream_t stream) {
    const float* embedding = (const float*)d_in[0];
    const int*   edges     = (const int*)d_in[1];
    const float* u         = (const float*)d_in[2];
    const float* W_emb     = (const float*)d_in[3];
    const float* b_emb     = (const float*)d_in[4];
    const float* W_edge    = (const float*)d_in[5];
    const float* b_edge    = (const float*)d_in[6];
    float*       out       = (float*)d_out;

    // workspace layout
    char*   ws    = (char*)d_ws;
    __bf16* Wtb   = (__bf16*)ws;                      // 262,144 B
    float*  w_sym = (float*)(ws + 262144);            //   1,024 B
    float*  g     = (float*)(ws + 262144 + 1024);     // 200,000 B

    prep_kernel<<<33, 256, 0, stream>>>(W_emb, W_edge, Wtb, w_sym);

    gemm_g_kernel<<<782, 256, 0, stream>>>(embedding, Wtb, b_emb, w_sym, g);

    edge_kernel<<<NE / 256, 256, 0, stream>>>(g, edges, u, b_edge, out);
}

// Round 2
// 202.178 us; speedup vs baseline: 1.0140x; 1.0140x over previous
//
#include <hip/hip_runtime.h>
#include <hip/hip_bf16.h>

#define NN      50000
#define INDIM   512
#define HIDDEN  256
#define NE      800000
#define BIASF   0.0001f

typedef __attribute__((ext_vector_type(4))) float  f32x4;
typedef __attribute__((ext_vector_type(4))) int    i32x4;
typedef __attribute__((ext_vector_type(4))) __bf16 bf16x4;
typedef __attribute__((ext_vector_type(8))) __bf16 bf16x8;

// ---------------------------------------------------------------------------
// prep: blocks 0..31 : Wtb[n][k] = (bf16)W_emb[k][n] via coalesced LDS transpose
//       block  32    : w_sym[j] = 0.5*(We[j]+We[j+256])
// ---------------------------------------------------------------------------
__global__ __launch_bounds__(256) void prep_kernel(const float* __restrict__ W_emb,
                                                   const float* __restrict__ W_edge,
                                                   __bf16* __restrict__ Wtb,
                                                   float* __restrict__ w_sym) {
    const int b   = blockIdx.x;
    const int tid = threadIdx.x;
    if (b < 32) {
        __shared__ float t[64 * 65];
        const int kt = (b >> 2) * 64;
        const int nt = (b & 3) * 64;
        const int rr = tid >> 4;           // 0..15
        const int cc = (tid & 15) * 4;     // 0..60
#pragma unroll
        for (int p = 0; p < 4; ++p) {
            int r = p * 16 + rr;
            f32x4 v = *(const f32x4*)&W_emb[(size_t)(kt + r) * HIDDEN + nt + cc];
            t[(cc + 0) * 65 + r] = v[0];
            t[(cc + 1) * 65 + r] = v[1];
            t[(cc + 2) * 65 + r] = v[2];
            t[(cc + 3) * 65 + r] = v[3];
        }
        __syncthreads();
#pragma unroll
        for (int p = 0; p < 4; ++p) {
            int n = p * 16 + rr;
            bf16x4 o;
            o[0] = (__bf16)t[n * 65 + cc + 0];
            o[1] = (__bf16)t[n * 65 + cc + 1];
            o[2] = (__bf16)t[n * 65 + cc + 2];
            o[3] = (__bf16)t[n * 65 + cc + 3];
            *(bf16x4*)&Wtb[(size_t)(nt + n) * INDIM + kt + cc] = o;
        }
    } else {
        w_sym[tid] = 0.5f * (W_edge[tid] + W_edge[tid + HIDDEN]);
    }
}

// ---------------------------------------------------------------------------
// gemm_g v3: same data plan as v2 (reg-staged A -> bf16 swizzled LDS, B bf16x8
// straight from L2-hot Wtb, 2-chunk K=256 double-buffer, T14 issue-early/
// write-late prefetch), but 8 WAVES per block (512 thr), each wave owning a
// 32-col N-slice (acc 4x2). LDS unchanged (67.5 KB -> 2 blocks/CU), so
// occupancy doubles: 2 -> 4 waves/SIMD. Round-1 counters showed a pure
// latency-bound regime (Mfma 6.8%, VALU 5%, HBM 9%, occ 15.5%): per-kstep
// B global loads (L2 ~200-400cy) + A ds_reads were exposed with only 2
// waves/SIMD to switch between. VGPR budget ~110 fits the 128 cap that 16
// waves/CU requires [m69], declared via __launch_bounds__(512, 4).
//   g[m] = sum_n relu(emb[m]@W[:,n] + b[n]) * w_sym[n]
// ---------------------------------------------------------------------------
__global__ __launch_bounds__(512, 4) void gemm_g_kernel(const float* __restrict__ A,
                                                        const __bf16* __restrict__ Wtb,
                                                        const float* __restrict__ bias,
                                                        const float* __restrict__ w_sym,
                                                        float* __restrict__ g) {
    __shared__ __align__(16) __bf16 As[2][64 * 256];   // 2 x 32 KiB bf16
    __shared__ float red[8][64];                       // +2 KiB -> 2 blocks/CU

    const int tid  = threadIdx.x;
    const int lane = tid & 63;
    const int w    = tid >> 6;                   // wave id 0..7 = N-slice
    const int ml   = lane & 15, kq = lane >> 4;
    const int m0   = blockIdx.x * 64;
    const int sml  = (ml & 7) << 4;              // read-side swizzle constant

    f32x4 acc[4][2];
#pragma unroll
    for (int i = 0; i < 4; ++i)
#pragma unroll
        for (int j = 0; j < 2; ++j) acc[i][j] = (f32x4)0.0f;

    const __bf16* bp[2];
#pragma unroll
    for (int nt = 0; nt < 2; ++nt) {
        int col = w * 32 + nt * 16 + ml;
        bp[nt] = Wtb + (size_t)col * INDIM + kq * 8;
    }

    // wave w owns rows w*8..w*8+7; one full f32 row (1 KB) per wave-load.
    auto stage_load = [&](f32x4* st, int c) {
#pragma unroll
        for (int j = 0; j < 8; ++j) {
            int gr = m0 + w * 8 + j;
            if (gr > NN - 1) gr = NN - 1;        // M-tail clamp
            st[j] = *(const f32x4*)(A + (size_t)gr * INDIM + c * 256 + lane * 4);
        }
    };
    // cvt to bf16 in regs, ds_write_b64 one row per instr at swizzled slots
    auto stage_write = [&](const f32x4* st, int b) {
        char* lb = (char*)&As[b][0];
#pragma unroll
        for (int j = 0; j < 8; ++j) {
            int r = w * 8 + j;
            bf16x4 o;
            o[0] = (__bf16)st[j][0]; o[1] = (__bf16)st[j][1];
            o[2] = (__bf16)st[j][2]; o[3] = (__bf16)st[j][3];
            *(bf16x4*)(lb + r * 512 + ((lane * 8) ^ ((r & 7) << 4))) = o;
        }
    };
    // 8 ksteps of K=32; fragments are direct bf16x8 ds_read_b128 (no cvt)
    auto compute = [&](int b, int c) {
        const char* lb = (const char*)&As[b][0];
#pragma unroll
        for (int ks = 0; ks < 8; ++ks) {
            bf16x8 af[4], bfr[2];
            const int voff = (ks * 64 + kq * 16) ^ sml;
#pragma unroll
            for (int mt = 0; mt < 4; ++mt)
                af[mt] = *(const bf16x8*)(lb + (mt * 16 + ml) * 512 + voff);
#pragma unroll
            for (int nt = 0; nt < 2; ++nt)
                bfr[nt] = *(const bf16x8*)(bp[nt] + c * 256 + ks * 32);
#pragma unroll
            for (int mt = 0; mt < 4; ++mt)
#pragma unroll
                for (int nt = 0; nt < 2; ++nt)
                    acc[mt][nt] = __builtin_amdgcn_mfma_f32_16x16x32_bf16(
                        af[mt], bfr[nt], acc[mt][nt], 0, 0, 0);
        }
    };

    f32x4 st[8];                                // 32 VGPR staging block
    stage_load(st, 0);
    stage_write(st, 0);                         // incremental vmcnt waits
    __syncthreads();                            // chunk 0 visible to all waves

    stage_load(st, 1);                          // 8 KB/wave in flight across compute(0)
    __builtin_amdgcn_sched_barrier(0);          // pin prefetch above the MFMA cluster
    compute(0, 0);
    stage_write(st, 1);                         // loads ~arrived under compute(0)
    __syncthreads();
    compute(1, 1);

    // ---- epilogue: relu+dot w_sym, xor-reduce over ml lanes, cross-wave LDS ----
    // C/D layout: col = ml (N dim), row = kq*4 + reg (M dim) [verified m89/m91]
    float wsv[2], bcv[2];
#pragma unroll
    for (int nt = 0; nt < 2; ++nt) {
        int col = w * 32 + nt * 16 + ml;
        wsv[nt] = w_sym[col];
        bcv[nt] = bias[col];
    }
#pragma unroll
    for (int mt = 0; mt < 4; ++mt) {
#pragma unroll
        for (int r = 0; r < 4; ++r) {
            float s = 0.0f;
#pragma unroll
            for (int nt = 0; nt < 2; ++nt) {
                float x = acc[mt][nt][r] + bcv[nt];
                s = fmaf(fmaxf(x, 0.0f), wsv[nt], s);
            }
            s += __shfl_xor(s, 1);
            s += __shfl_xor(s, 2);
            s += __shfl_xor(s, 4);
            s += __shfl_xor(s, 8);
            if (ml == 0) red[w][mt * 16 + kq * 4 + r] = s;
        }
    }
    __syncthreads();
    if (tid < 64) {
        int row = m0 + tid;
        if (row < NN)
            g[row] = red[0][tid] + red[1][tid] + red[2][tid] + red[3][tid]
                   + red[4][tid] + red[5][tid] + red[6][tid] + red[7][tid];
    }
}

// ---------------------------------------------------------------------------
// edge kernel: 4 edges per thread, vectorized int4/f32x4 streams; g gathers
// are 4B L2 hits in a 200 KB array. Fused gumbel-sigmoid:
// sigmoid(log(eps)-log1p(-eps)+raw) = 1/(1+(1/eps-1)e^-raw)
// ---------------------------------------------------------------------------
__global__ __launch_bounds__(256) void edge_kernel(const float* __restrict__ g,
                                                   const int* __restrict__ edges,
                                                   const float* __restrict__ u,
                                                   const float* __restrict__ b_edge,
                                                   float* __restrict__ out) {
    const int e = (blockIdx.x * 256 + threadIdx.x) * 4;
    if (e >= NE) return;                         // NE % 4 == 0: full quads only
    i32x4 i0 = *(const i32x4*)&edges[e];
    i32x4 i1 = *(const i32x4*)&edges[NE + e];
    f32x4 uu = *(const f32x4*)&u[e];
    const float be = b_edge[0];
    f32x4 o;
#pragma unroll
    for (int j = 0; j < 4; ++j) {
        float raw = g[i0[j]] + g[i1[j]] + be;
        float eps = fmaf(uu[j], BIASF - (1.0f - BIASF), 1.0f - BIASF);
        float q   = 1.0f / eps - 1.0f;           // (1-eps)/eps in (1e-4, 1e4)
        float t   = __expf(-raw);
        o[j] = 1.0f / fmaf(q, t, 1.0f);
    }
    *(f32x4*)&out[e] = o;
}

// ---------------------------------------------------------------------------
extern "C" void kernel_launch(void* const* d_in, const int* in_sizes, int n_in,
                              void* d_out, int out_size, void* d_ws, size_t ws_size,
                              hipStream_t stream) {
    const float* embedding = (const float*)d_in[0];
    const int*   edges     = (const int*)d_in[1];
    const float* u         = (const float*)d_in[2];
    const float* W_emb     = (const float*)d_in[3];
    const float* b_emb     = (const float*)d_in[4];
    const float* W_edge    = (const float*)d_in[5];
    const float* b_edge    = (const float*)d_in[6];
    float*       out       = (float*)d_out;

    // workspace layout
    char*   ws    = (char*)d_ws;
    __bf16* Wtb   = (__bf16*)ws;                      // 262,144 B
    float*  w_sym = (float*)(ws + 262144);            //   1,024 B
    float*  g     = (float*)(ws + 262144 + 1024);     // 200,000 B

    prep_kernel<<<33, 256, 0, stream>>>(W_emb, W_edge, Wtb, w_sym);

    gemm_g_kernel<<<782, 512, 0, stream>>>(embedding, Wtb, b_emb, w_sym, g);

    edge_kernel<<<(NE / 4 + 255) / 256, 256, 0, stream>>>(g, edges, u, b_edge, out);
}

// Round 3
// 188.104 us; speedup vs baseline: 1.0899x; 1.0748x over previous
//
#include <hip/hip_runtime.h>
#include <hip/hip_bf16.h>

#define NN      50000
#define INDIM   512
#define HIDDEN  256
#define NE      800000
#define BIASF   0.0001f

typedef __attribute__((ext_vector_type(4))) float  f32x4;
typedef __attribute__((ext_vector_type(4))) __bf16 bf16x4;
typedef __attribute__((ext_vector_type(8))) __bf16 bf16x8;

// ---------------------------------------------------------------------------
// prep: blocks 0..31 : Wtb[n][k] = (bf16)W_emb[k][n] via coalesced LDS transpose
//       block  32    : w_sym[j] = 0.5*(We[j]+We[j+256])
// ---------------------------------------------------------------------------
__global__ __launch_bounds__(256) void prep_kernel(const float* __restrict__ W_emb,
                                                   const float* __restrict__ W_edge,
                                                   __bf16* __restrict__ Wtb,
                                                   float* __restrict__ w_sym) {
    const int b   = blockIdx.x;
    const int tid = threadIdx.x;
    if (b < 32) {
        __shared__ float t[64 * 65];
        const int kt = (b >> 2) * 64;
        const int nt = (b & 3) * 64;
        const int rr = tid >> 4;           // 0..15
        const int cc = (tid & 15) * 4;     // 0..60
#pragma unroll
        for (int p = 0; p < 4; ++p) {
            int r = p * 16 + rr;
            f32x4 v = *(const f32x4*)&W_emb[(size_t)(kt + r) * HIDDEN + nt + cc];
            t[(cc + 0) * 65 + r] = v[0];
            t[(cc + 1) * 65 + r] = v[1];
            t[(cc + 2) * 65 + r] = v[2];
            t[(cc + 3) * 65 + r] = v[3];
        }
        __syncthreads();
#pragma unroll
        for (int p = 0; p < 4; ++p) {
            int n = p * 16 + rr;
            bf16x4 o;
            o[0] = (__bf16)t[n * 65 + cc + 0];
            o[1] = (__bf16)t[n * 65 + cc + 1];
            o[2] = (__bf16)t[n * 65 + cc + 2];
            o[3] = (__bf16)t[n * 65 + cc + 3];
            *(bf16x4*)&Wtb[(size_t)(nt + n) * INDIM + kt + cc] = o;
        }
    } else {
        w_sym[tid] = 0.5f * (W_edge[tid] + W_edge[tid + HIDDEN]);
    }
}

// ---------------------------------------------------------------------------
// gemm_g v4: vmcnt-poison-free pipeline. Round-2 post-mortem: vmcnt retires
// IN ISSUE ORDER [m135], so r2's "prefetch A then compute" made every B-frag
// consumption in compute wait behind the younger... OLDER 8 HBM A-loads ->
// every k-step serialized on HBM latency; occupancy couldn't fix it.
// v4: 4 chunks of K=128. Per chunk: B-frags hoisted to regs FIRST (L2-fast,
// oldest), THEN next-chunk A prefetch issued (HBM, younger), THEN compute
// (pure ds_read+MFMA; B retires without draining A). A drains under the
// next stage_write's counted waits, covered by compute. Register budget:
// acc 32 + B 32 + st 16 + af 16 + addr ~ 120 <= 128-VGPR cap for
// 2 blocks/CU x 512 thr = 16 waves/CU. LDS 34 KB.
//   g[m] = sum_n relu(emb[m]@W[:,n] + b[n]) * w_sym[n]
// ---------------------------------------------------------------------------
__global__ __launch_bounds__(512, 4) void gemm_g_kernel(const float* __restrict__ A,
                                                        const __bf16* __restrict__ Wtb,
                                                        const float* __restrict__ bias,
                                                        const float* __restrict__ w_sym,
                                                        float* __restrict__ g) {
    __shared__ __align__(16) __bf16 As[2][64 * 128];   // 2 x 16 KiB bf16
    __shared__ float red[8][64];                       // -> ~34 KB total

    const int tid  = threadIdx.x;
    const int lane = tid & 63;
    const int w    = tid >> 6;                   // wave id 0..7 = N-slice (32 cols)
    const int ml   = lane & 15, kq = lane >> 4;
    const int l5   = lane >> 5;                  // row parity within a 1KB DMA pair
    const int lk   = lane & 31;                  // 16B column within the row-pair
    const int m0   = blockIdx.x * 64;
    const int sml  = (ml & 7) << 4;              // read-side swizzle constant

    f32x4 acc[4][2];
#pragma unroll
    for (int i = 0; i < 4; ++i)
#pragma unroll
        for (int j = 0; j < 2; ++j) acc[i][j] = (f32x4)0.0f;

    const __bf16* bp[2];
#pragma unroll
    for (int nt = 0; nt < 2; ++nt) {
        int col = w * 32 + nt * 16 + ml;
        bp[nt] = Wtb + (size_t)col * INDIM + kq * 8;
    }

    // stage chunk c: wave owns rows w*8..w*8+7; 2 rows (512B each) per instr.
    auto stage_load = [&](f32x4* st, int c) {
#pragma unroll
        for (int j = 0; j < 4; ++j) {
            int gr = m0 + w * 8 + 2 * j + l5;
            if (gr > NN - 1) gr = NN - 1;        // M-tail clamp
            st[j] = *(const f32x4*)(A + (size_t)gr * INDIM + c * 128 + lk * 4);
        }
    };
    // cvt to bf16 in regs, ds_write_b64 at XOR-swizzled slots (row stride 256B)
    auto stage_write = [&](const f32x4* st, int b) {
        char* lb = (char*)&As[b][0];
#pragma unroll
        for (int j = 0; j < 4; ++j) {
            int r = w * 8 + 2 * j + l5;
            bf16x4 o;
            o[0] = (__bf16)st[j][0]; o[1] = (__bf16)st[j][1];
            o[2] = (__bf16)st[j][2]; o[3] = (__bf16)st[j][3];
            *(bf16x4*)(lb + r * 256 + ((lk * 8) ^ ((r & 7) << 4))) = o;
        }
    };
    // hoist a full chunk of B (32 cols x 128 k) into 32 VGPRs — L2-hot Wtb
    auto loadB = [&](bf16x8* bfr, int c) {
#pragma unroll
        for (int ks = 0; ks < 4; ++ks)
#pragma unroll
            for (int nt = 0; nt < 2; ++nt)
                bfr[ks * 2 + nt] = *(const bf16x8*)(bp[nt] + c * 128 + ks * 32);
    };
    // pure LDS+MFMA compute: 4 ksteps of K=32, zero VMEM ops inside
    auto compute = [&](int b, const bf16x8* bfr) {
        const char* lb = (const char*)&As[b][0];
#pragma unroll
        for (int ks = 0; ks < 4; ++ks) {
            bf16x8 af[4];
            const int voff = (ks * 64 + kq * 16) ^ sml;
#pragma unroll
            for (int mt = 0; mt < 4; ++mt)
                af[mt] = *(const bf16x8*)(lb + (mt * 16 + ml) * 256 + voff);
#pragma unroll
            for (int mt = 0; mt < 4; ++mt)
#pragma unroll
                for (int nt = 0; nt < 2; ++nt)
                    acc[mt][nt] = __builtin_amdgcn_mfma_f32_16x16x32_bf16(
                        af[mt], bfr[ks * 2 + nt], acc[mt][nt], 0, 0, 0);
        }
    };

    f32x4  st[4];                               // 16 VGPR A staging
    bf16x8 bfr[8];                              // 32 VGPR B chunk

    stage_load(st, 0);
    stage_write(st, 0);                         // counted vmcnt drains A0
    __syncthreads();

    loadB(bfr, 0);                              // B0 first: oldest in vmcnt order
    __builtin_amdgcn_sched_barrier(0);
    stage_load(st, 1);                          // A1 younger -> can't block B0
    __builtin_amdgcn_sched_barrier(0);

#pragma unroll
    for (int c = 0; c < 4; ++c) {
        compute(c & 1, bfr);                    // VMEM-free; B_c retires cleanly
        if (c < 3) {
            loadB(bfr, c + 1);                  // B_{c+1} before A_{c+2} in issue order
            __builtin_amdgcn_sched_barrier(0);
            stage_write(st, (c + 1) & 1);       // waits drain A_{c+1} only (older)
            __syncthreads();
            if (c < 2) {
                stage_load(st, c + 2);          // next HBM prefetch, youngest
                __builtin_amdgcn_sched_barrier(0);
            }
        }
    }

    // ---- epilogue: relu+dot w_sym, xor-reduce over ml lanes, cross-wave LDS ----
    // C/D layout: col = ml (N dim), row = kq*4 + reg (M dim) [verified m89/m91]
    float wsv[2], bcv[2];
#pragma unroll
    for (int nt = 0; nt < 2; ++nt) {
        int col = w * 32 + nt * 16 + ml;
        wsv[nt] = w_sym[col];
        bcv[nt] = bias[col];
    }
#pragma unroll
    for (int mt = 0; mt < 4; ++mt) {
#pragma unroll
        for (int r = 0; r < 4; ++r) {
            float s = 0.0f;
#pragma unroll
            for (int nt = 0; nt < 2; ++nt) {
                float x = acc[mt][nt][r] + bcv[nt];
                s = fmaf(fmaxf(x, 0.0f), wsv[nt], s);
            }
            s += __shfl_xor(s, 1);
            s += __shfl_xor(s, 2);
            s += __shfl_xor(s, 4);
            s += __shfl_xor(s, 8);
            if (ml == 0) red[w][mt * 16 + kq * 4 + r] = s;
        }
    }
    __syncthreads();
    if (tid < 64) {
        int row = m0 + tid;
        if (row < NN)
            g[row] = red[0][tid] + red[1][tid] + red[2][tid] + red[3][tid]
                   + red[4][tid] + red[5][tid] + red[6][tid] + red[7][tid];
    }
}

// ---------------------------------------------------------------------------
// edge kernel: one thread per edge; g gathers are 4B L2 hits in a 200 KB array.
// Fast-path transcendentals only: sigmoid(raw + log(eps/(1-eps))).
// ---------------------------------------------------------------------------
__global__ __launch_bounds__(256) void edge_kernel(const float* __restrict__ g,
                                                   const int* __restrict__ edges,
                                                   const float* __restrict__ u,
                                                   const float* __restrict__ b_edge,
                                                   float* __restrict__ out) {
    const int e  = blockIdx.x * 256 + threadIdx.x;      // NE = 3125*256 exactly
    const int i0 = edges[e];
    const int i1 = edges[NE + e];
    float raw = g[i0] + g[i1] + b_edge[0];
    float uu  = u[e];
    float eps = fmaf(uu, BIASF - (1.0f - BIASF), 1.0f - BIASF); // in (1e-4, 0.9999)
    float lg  = __logf(eps) - __logf(1.0f - eps);
    float t   = __expf(-(raw + lg));
    out[e] = __fdividef(1.0f, 1.0f + t);
}

// ---------------------------------------------------------------------------
extern "C" void kernel_launch(void* const* d_in, const int* in_sizes, int n_in,
                              void* d_out, int out_size, void* d_ws, size_t ws_size,
                              hipStream_t stream) {
    const float* embedding = (const float*)d_in[0];
    const int*   edges     = (const int*)d_in[1];
    const float* u         = (const float*)d_in[2];
    const float* W_emb     = (const float*)d_in[3];
    const float* b_emb     = (const float*)d_in[4];
    const float* W_edge    = (const float*)d_in[5];
    const float* b_edge    = (const float*)d_in[6];
    float*       out       = (float*)d_out;

    // workspace layout
    char*   ws    = (char*)d_ws;
    __bf16* Wtb   = (__bf16*)ws;                      // 262,144 B
    float*  w_sym = (float*)(ws + 262144);            //   1,024 B
    float*  g     = (float*)(ws + 262144 + 1024);     // 200,000 B

    prep_kernel<<<33, 256, 0, stream>>>(W_emb, W_edge, Wtb, w_sym);

    gemm_g_kernel<<<782, 512, 0, stream>>>(embedding, Wtb, b_emb, w_sym, g);

    edge_kernel<<<NE / 256, 256, 0, stream>>>(g, edges, u, b_edge, out);
}